// Round 8
// baseline (227.483 us; speedup 1.0000x reference)
//
#include <hip/hip_runtime.h>

#define B_ 8
#define S_ 32
#define C_ 3
#define H_ 256
#define W_ 256
#define HW_ (H_*W_)
#define CHW_ (C_*H_*W_)
#define NT_ 24            // K-tiles of 32
#define TILE_ELEMS 8192   // 256 rows x 32 k per pre-split B tile

typedef __attribute__((ext_vector_type(8))) short bf16x8;
typedef __attribute__((ext_vector_type(4))) float f32x4;
typedef unsigned int u32;
typedef u32 __attribute__((address_space(3)))* lds_u32p;
typedef const u32 __attribute__((address_space(1)))* glb_u32p;

// truncation-based hi/lo bf16 split of two floats, packed (x low half, y high)
__device__ __forceinline__ void split2(float x, float y, unsigned &hp, unsigned &lp) {
  unsigned ux = __float_as_uint(x), uy = __float_as_uint(y);
  unsigned hx = ux & 0xFFFF0000u, hy = uy & 0xFFFF0000u;
  float lx = x - __uint_as_float(hx);
  float ly = y - __uint_as_float(hy);
  hp = (ux >> 16) | hy;
  lp = (__float_as_uint(lx) >> 16) | (__float_as_uint(ly) & 0xFFFF0000u);
}

__device__ __forceinline__ void gl2lds16(const ushort* g, ushort* l) {
  __builtin_amdgcn_global_load_lds((glb_u32p)g, (lds_u32p)l, 16, 0, 0);
}

// -------- target row reciprocal norms (one wave per 768-elem row) --------
__global__ void ct_ntg(const float* __restrict__ target, float* __restrict__ rntg) {
  int r = (int)((blockIdx.x * (size_t)blockDim.x + threadIdx.x) >> 6);  // 0..2047
  int lane = threadIdx.x & 63;
  const float* base = target + (size_t)(r >> 8) * CHW_ + (size_t)(r & 255) * W_;
  float ss = 0.f;
#pragma unroll
  for (int c = 0; c < C_; ++c)
#pragma unroll
    for (int tt = 0; tt < W_/64; ++tt) {
      float v = base[c*HW_ + tt*64 + lane];
      ss = fmaf(v, v, ss);
    }
#pragma unroll
  for (int off = 32; off; off >>= 1) ss += __shfl_xor(ss, off);
  if (lane == 0) rntg[r] = 1.0f / fmaxf(sqrtf(ss), 1e-12f);
}

// -------- target -> bf16 hi/lo, per-(b,ktile32) fragment layout --------
__global__ void ct_bsplit(const float* __restrict__ target,
                          ushort* __restrict__ BhG, ushort* __restrict__ BlG) {
  int bx = blockIdx.x;             // b*24 + kt
  int b  = bx / 24, kt = bx % 24;
  int c  = kt >> 3, w0 = (kt & 7) * 32;
  int t  = threadIdx.x;
  int trow = t >> 3, tw = t & 7;   // 8 threads per row, 4 floats each
  const float* base = target + (size_t)(b*C_ + c) * HW_ + w0 + tw*4;
  ushort* oh = BhG + (size_t)bx * TILE_ELEMS;
  ushort* ol = BlG + (size_t)bx * TILE_ELEMS;
#pragma unroll
  for (int i = 0; i < 8; ++i) {
    int row = trow + 32*i;
    float4 v = *(const float4*)(base + (size_t)row * W_);
    unsigned h0, l0, h1, l1;
    split2(v.x, v.y, h0, l0); split2(v.z, v.w, h1, l1);
    int idx = (row>>4)*512 + (tw>>1)*128 + (row&15)*8 + (tw&1)*4;
    *(uint2*)&oh[idx] = make_uint2(h0, h1);
    *(uint2*)&ol[idx] = make_uint2(l0, l1);
  }
}

// -------- fused corr: M-split x4, block 64x256, K=768, bf16 3-term split --------
// grid = bs(256) x mb(4), 512 threads = 8 waves (wm 0..1 x wn 0..3), wave tile 32x64.
// acc[2][4] = 32 AGPR; VGPR+AGPR <= 128 -> 16 waves/CU (2 blocks co-resident).
// A: reg-staged 1 float4/thread (fused row-norm partials). B: per-wave-panel DMA
// from pre-split global (zero regs, zero VALU). Plain 2-barrier loop, no asm pins.
__global__ __launch_bounds__(512, 4)
void ct_corr_mfma(const float* __restrict__ input,
                  const ushort* __restrict__ BhG, const ushort* __restrict__ BlG,
                  const float* __restrict__ rntg_g,
                  float* __restrict__ corrP) {
  __shared__ ushort AhL[2048], AlL[2048];     // 64 rows x 32 k (4 KB each)
  __shared__ ushort BhL[8192], BlL[8192];     // 256 cols x 32 k (16 KB each)
  __shared__ float ninSq[64], rnin[64], corrS[256];

  const int bx = blockIdx.x;
  const int bs = bx >> 2;          // b*S + s  (same-b blocks contiguous -> B L2 reuse)
  const int mb = bx & 3;           // row quarter
  const int bG = bs >> 5;
  const int t  = threadIdx.x;      // 0..511
  const int lane = t & 63;
  const int wid  = t >> 6;
  const int wm   = wid >> 2;       // 0..1 : 32-row half
  const int wn   = wid & 3;        // 0..3 : 64-col panel

  const float* Abase = input + (size_t)bs * CHW_ + (size_t)(mb * 64) * W_;

  if (t < 64) ninSq[t] = 0.f;
  if (t < 256) corrS[t] = 0.f;

  f32x4 acc[2][4];
#pragma unroll
  for (int m = 0; m < 2; ++m)
#pragma unroll
    for (int n = 0; n < 4; ++n) acc[m][n] = (f32x4){0.f, 0.f, 0.f, 0.f};

  // thread's fixed A coordinates (same row every tile; k-slot varies by tile)
  const int lrow = ((t >> 7) & 3) * 16 + ((t >> 1) & 15);   // 0..63
  const int kk   = ((t >> 5) & 3) * 8 + (t & 1) * 4;        // 0..28
  const int aidx = ((t >> 7) & 3) * 512 + ((t >> 5) & 3) * 128
                 + ((t >> 1) & 15) * 8 + (t & 1) * 4;       // LDS frag addr

  float4 pa;
  float ssA = 0.f;

  // prefetch A tile 0
  pa = *(const float4*)(Abase + (size_t)lrow * W_ + kk);

  for (int kt = 0; kt < NT_; ++kt) {
    __syncthreads();               // prev tile's LDS reads done; pa landed
    // B DMA: wave loads ONLY its own 64-col panel (hi+lo), own-vmcnt covered
    {
      const ushort* gh = BhG + (size_t)(bG*NT_ + kt) * TILE_ELEMS + wn*2048;
      const ushort* gl = BlG + (size_t)(bG*NT_ + kt) * TILE_ELEMS + wn*2048;
#pragma unroll
      for (int o = 0; o < 4; ++o)
        gl2lds16(gh + o*512 + lane*8, &BhL[wn*2048 + o*512]);
#pragma unroll
      for (int o = 0; o < 4; ++o)
        gl2lds16(gl + o*512 + lane*8, &BlL[wn*2048 + o*512]);
    }
    // stash A (convert f32 -> hi/lo bf16) + fused norm partial
    {
      float4 va = pa;
      ssA = fmaf(va.x, va.x, fmaf(va.y, va.y,
            fmaf(va.z, va.z, fmaf(va.w, va.w, ssA))));
      unsigned h0, l0, h1, l1;
      split2(va.x, va.y, h0, l0); split2(va.z, va.w, h1, l1);
      *(uint2*)&AhL[aidx] = make_uint2(h0, h1);
      *(uint2*)&AlL[aidx] = make_uint2(l0, l1);
    }
    __syncthreads();               // stash ds_writes + B DMA drained
    if (kt < NT_ - 1) {            // prefetch next A tile (lands during MFMA+barrier)
      const float* Ab = Abase + (size_t)((kt+1) >> 3) * HW_ + ((kt+1) & 7) * 32;
      pa = *(const float4*)(Ab + (size_t)lrow * W_ + kk);
    }

    bf16x8 bh[4], bl[4];
#pragma unroll
    for (int n = 0; n < 4; ++n) {
      int ct = wn*4 + n;
      bh[n] = *(const bf16x8*)&BhL[ct*512 + lane*8];
      bl[n] = *(const bf16x8*)&BlL[ct*512 + lane*8];
    }
#pragma unroll
    for (int m = 0; m < 2; ++m) {
      int rt = wm*2 + m;
      bf16x8 ah = *(const bf16x8*)&AhL[rt*512 + lane*8];
      bf16x8 al = *(const bf16x8*)&AlL[rt*512 + lane*8];
#pragma unroll
      for (int n = 0; n < 4; ++n) {
        acc[m][n] = __builtin_amdgcn_mfma_f32_16x16x32_bf16(ah, bh[n], acc[m][n], 0, 0, 0);
        acc[m][n] = __builtin_amdgcn_mfma_f32_16x16x32_bf16(ah, bl[n], acc[m][n], 0, 0, 0);
        acc[m][n] = __builtin_amdgcn_mfma_f32_16x16x32_bf16(al, bh[n], acc[m][n], 0, 0, 0);
      }
    }
  }

  // fused A-norms: 8 threads contributed per row
  atomicAdd(&ninSq[lrow], ssA);
  __syncthreads();
  if (t < 64) rnin[t] = 1.0f / fmaxf(sqrtf(ninSq[t]), 1e-12f);
  __syncthreads();

  // normalize + reduce upper diagonals into LDS (q = col - grow >= 0)
#pragma unroll
  for (int n = 0; n < 4; ++n) {
    int col = wn*64 + n*16 + (lane & 15);
    float rc = rntg_g[bG*256 + col];
#pragma unroll
    for (int m = 0; m < 2; ++m) {
      f32x4 a = acc[m][n];
#pragma unroll
      for (int r = 0; r < 4; ++r) {
        int lr = wm*32 + m*16 + (lane >> 4)*4 + r;
        int q = col - (mb*64 + lr);
        if (q >= 0) atomicAdd(&corrS[q], a[r] * rnin[lr] * rc);
      }
    }
  }
  __syncthreads();

  // deterministic partial write: one slice per (bs, mb)
  if (t < 256) corrP[bs*1024 + mb*256 + t] = corrS[t];
}

// -------- argmax over p (sum 4 partials; first max = smallest p wins) --------
__global__ void ct_argmax(const float* __restrict__ corrP, int* __restrict__ shift) {
  int bs = blockIdx.x;
  int lane = threadIdx.x;          // 0..63
  unsigned long long key = 0;
#pragma unroll
  for (int i = 0; i < 4; ++i) {
    int q = lane + 64*i;
    const float* p = corrP + bs*1024 + q;
    float v = (p[0] + p[256] + p[512] + p[768]) / (float)(256 - q);
    unsigned u = __float_as_uint(v);
    u = (u & 0x80000000u) ? ~u : (u | 0x80000000u);
    unsigned long long k = ((unsigned long long)u << 32) | (unsigned)q;
    if (k > key) key = k;
  }
#pragma unroll
  for (int off = 32; off; off >>= 1) {
    unsigned long long o = __shfl_xor(key, off);
    if (o > key) key = o;
  }
  if (lane == 0) shift[bs] = (int)(key & 0xFFFFFFFFull);
}

// -------- shifted gather --------
__global__ void ct_gather(const float* __restrict__ input,
                          const int* __restrict__ shift,
                          float* __restrict__ out) {
  size_t idx = (size_t)blockIdx.x * blockDim.x + threadIdx.x;  // float4 units
  int w4 = (int)(idx & 63);
  int h  = (int)((idx >> 6) & 255);
  int sc = (int)(idx >> 14);
  int bs = sc / 3;
  int hh = h + shift[bs];
  float4 v = make_float4(0.f, 0.f, 0.f, 0.f);
  if (hh < H_) v = *(const float4*)(input + ((size_t)sc << 16) + (size_t)hh * W_ + w4*4);
  *(float4*)(out + (idx << 2)) = v;
}

extern "C" void kernel_launch(void* const* d_in, const int* in_sizes, int n_in,
                              void* d_out, int out_size, void* d_ws, size_t ws_size,
                              hipStream_t stream) {
  const float* input  = (const float*)d_in[0];
  const float* target = (const float*)d_in[1];
  float* out = (float*)d_out;

  float* rntg  = (float*)d_ws;                      // 2048 f
  int*   shift = (int*)(rntg + 2048);               // 256 i
  float* corrP = (float*)(shift + 256);             // 256*4*256 f = 1 MB
  ushort* BhG  = (ushort*)(corrP + 256*1024);       // 8*24*8192 ushort = 3 MB
  ushort* BlG  = BhG + (size_t)B_ * NT_ * TILE_ELEMS;

  ct_ntg       <<<512, 256, 0, stream>>>(target, rntg);
  ct_bsplit    <<<B_ * NT_, 256, 0, stream>>>(target, BhG, BlG);
  ct_corr_mfma <<<B_ * S_ * 4, 512, 0, stream>>>(input, BhG, BlG, rntg, corrP);
  ct_argmax    <<<B_ * S_, 64, 0, stream>>>(corrP, shift);
  ct_gather    <<<(B_*S_*C_*H_*W_/4) / 256, 256, 0, stream>>>(input, shift, out);
}

// Round 9
// 173.319 us; speedup vs baseline: 1.3125x; 1.3125x over previous
//
#include <hip/hip_runtime.h>

#define B_ 8
#define S_ 32
#define C_ 3
#define H_ 256
#define W_ 256
#define HW_ (H_*W_)
#define CHW_ (C_*H_*W_)
#define NT_ 24            // K-tiles of 32
#define TILE_ELEMS 8192   // 256 rows x 32 k per pre-split B tile

typedef __attribute__((ext_vector_type(8))) short bf16x8;
typedef __attribute__((ext_vector_type(4))) float f32x4;
typedef unsigned int u32;
typedef u32 __attribute__((address_space(3)))* lds_u32p;
typedef const u32 __attribute__((address_space(1)))* glb_u32p;

// truncation-based hi/lo bf16 split of two floats, packed (x low half, y high)
__device__ __forceinline__ void split2(float x, float y, unsigned &hp, unsigned &lp) {
  unsigned ux = __float_as_uint(x), uy = __float_as_uint(y);
  unsigned hx = ux & 0xFFFF0000u, hy = uy & 0xFFFF0000u;
  float lx = x - __uint_as_float(hx);
  float ly = y - __uint_as_float(hy);
  hp = (ux >> 16) | hy;
  lp = (__float_as_uint(lx) >> 16) | (__float_as_uint(ly) & 0xFFFF0000u);
}

__device__ __forceinline__ void gl2lds16(const ushort* g, ushort* l) {
  __builtin_amdgcn_global_load_lds((glb_u32p)g, (lds_u32p)l, 16, 0, 0);
}

// -------- target row reciprocal norms (one wave per 768-elem row) --------
__global__ void ct_ntg(const float* __restrict__ target, float* __restrict__ rntg) {
  int r = (int)((blockIdx.x * (size_t)blockDim.x + threadIdx.x) >> 6);  // 0..2047
  int lane = threadIdx.x & 63;
  const float* base = target + (size_t)(r >> 8) * CHW_ + (size_t)(r & 255) * W_;
  float ss = 0.f;
#pragma unroll
  for (int c = 0; c < C_; ++c)
#pragma unroll
    for (int tt = 0; tt < W_/64; ++tt) {
      float v = base[c*HW_ + tt*64 + lane];
      ss = fmaf(v, v, ss);
    }
#pragma unroll
  for (int off = 32; off; off >>= 1) ss += __shfl_xor(ss, off);
  if (lane == 0) rntg[r] = 1.0f / fmaxf(sqrtf(ss), 1e-12f);
}

// -------- target -> bf16 hi/lo, per-(b,ktile32) fragment layout --------
__global__ void ct_bsplit(const float* __restrict__ target,
                          ushort* __restrict__ BhG, ushort* __restrict__ BlG) {
  int bx = blockIdx.x;             // b*24 + kt
  int b  = bx / 24, kt = bx % 24;
  int c  = kt >> 3, w0 = (kt & 7) * 32;
  int t  = threadIdx.x;
  int trow = t >> 3, tw = t & 7;   // 8 threads per row, 4 floats each
  const float* base = target + (size_t)(b*C_ + c) * HW_ + w0 + tw*4;
  ushort* oh = BhG + (size_t)bx * TILE_ELEMS;
  ushort* ol = BlG + (size_t)bx * TILE_ELEMS;
#pragma unroll
  for (int i = 0; i < 8; ++i) {
    int row = trow + 32*i;
    float4 v = *(const float4*)(base + (size_t)row * W_);
    unsigned h0, l0, h1, l1;
    split2(v.x, v.y, h0, l0); split2(v.z, v.w, h1, l1);
    int idx = (row>>4)*512 + (tw>>1)*128 + (row&15)*8 + (tw&1)*4;
    *(uint2*)&oh[idx] = make_uint2(h0, h1);
    *(uint2*)&ol[idx] = make_uint2(l0, l1);
  }
}

// -------- fused corr: per-(b,s) 256x256 MFMA GEMM (K=768, bf16 3-term split)
//          + fused A-norms + diagonal reduce + argmax --------
// EXACT round-2 structure (best measured): grid 256, 8 waves, wave tile 128x64,
// BK=32, single LDS buffer, plain 2-barrier loop, compiler-scheduled.
// Changes vs r2: B staged via global_load_lds DMA from pre-split global
// (no B VALU/regs), A-norms fused into stash, trunc split.
__global__ __launch_bounds__(512)
void ct_corr_mfma(const float* __restrict__ input,
                  const ushort* __restrict__ BhG, const ushort* __restrict__ BlG,
                  const float* __restrict__ rntg_g,
                  int* __restrict__ shift_out) {
  __shared__ ushort AhL[8192], AlL[8192], BhL[8192], BlL[8192];  // 64 KB
  __shared__ float ninSq[256], rnin[256], rntg_s[256], corrS[256];
  __shared__ unsigned long long wkey[4];

  const int bs = blockIdx.x;          // b*S + s
  const int bG = bs >> 5;
  const int t  = threadIdx.x;         // 0..511
  const int lane = t & 63;
  const int wid  = t >> 6;            // 0..7
  const int wm   = wid >> 2;          // 0..1 : M half (128 rows)
  const int wn   = wid & 3;           // 0..3 : N quarter (64 cols)

  const float* Abase = input + (size_t)bs * CHW_;

  if (t < 256) { ninSq[t] = 0.f; corrS[t] = 0.f; rntg_s[t] = rntg_g[bG*256 + t]; }

  f32x4 acc[8][4];
#pragma unroll
  for (int m = 0; m < 8; ++m)
#pragma unroll
    for (int n = 0; n < 4; ++n) acc[m][n] = (f32x4){0.f, 0.f, 0.f, 0.f};

  float4 pa[4];
  float ssA[4] = {0.f, 0.f, 0.f, 0.f};

  // A map (r2): f = p*512+t; row=(f>>7)*16+((f>>1)&15); kk=((f>>5)&3)*8+(f&1)*4
  auto issueA = [&](int kt) {
    const float* Ab = Abase + (size_t)(kt >> 3) * HW_ + (kt & 7) * 32;
#pragma unroll
    for (int p = 0; p < 4; ++p) {
      int f   = p * 512 + t;
      int row = (f >> 7) * 16 + ((f >> 1) & 15);
      int kk  = ((f >> 5) & 3) * 8 + (f & 1) * 4;
      pa[p] = *(const float4*)(Ab + (size_t)row * W_ + kk);
    }
  };

  auto stashA = [&]() {
#pragma unroll
    for (int p = 0; p < 4; ++p) {
      int f   = p * 512 + t;
      int idx = (f >> 7) * 512 + ((f >> 5) & 3) * 128 + ((f >> 1) & 15) * 8 + (f & 1) * 4;
      float4 va = pa[p];
      ssA[p] = fmaf(va.x, va.x, fmaf(va.y, va.y,
               fmaf(va.z, va.z, fmaf(va.w, va.w, ssA[p]))));
      unsigned h0, l0, h1, l1;
      split2(va.x, va.y, h0, l0); split2(va.z, va.w, h1, l1);
      *(uint2*)&AhL[idx] = make_uint2(h0, h1);
      *(uint2*)&AlL[idx] = make_uint2(l0, l1);
    }
  };

  issueA(0);

  for (int kt = 0; kt < NT_; ++kt) {
    __syncthreads();                  // prev tile's LDS reads done; pa(kt) landed
    // B DMA: wm=0 waves each load one 64-col panel (hi+lo). Their own vmcnt
    // drains before the next barrier -> B in LDS for everyone after it.
    if (wid < 4) {
      const ushort* gh = BhG + (size_t)(bG*NT_ + kt) * TILE_ELEMS + wid*2048;
      const ushort* gl = BlG + (size_t)(bG*NT_ + kt) * TILE_ELEMS + wid*2048;
#pragma unroll
      for (int o = 0; o < 4; ++o)
        gl2lds16(gh + o*512 + lane*8, &BhL[wid*2048 + o*512]);
#pragma unroll
      for (int o = 0; o < 4; ++o)
        gl2lds16(gl + o*512 + lane*8, &BlL[wid*2048 + o*512]);
    }
    stashA();                         // convert + fused norm partials
    __syncthreads();                  // ds_writes + B DMA drained (compiler)
    if (kt < NT_ - 1) issueA(kt + 1); // prefetch next A under MFMA

    bf16x8 bh[4], bl[4];
#pragma unroll
    for (int n = 0; n < 4; ++n) {
      int ct = wn * 4 + n;
      bh[n] = *(const bf16x8*)&BhL[ct * 512 + lane * 8];
      bl[n] = *(const bf16x8*)&BlL[ct * 512 + lane * 8];
    }
#pragma unroll
    for (int m = 0; m < 8; ++m) {
      int rt = wm * 8 + m;
      bf16x8 ah = *(const bf16x8*)&AhL[rt * 512 + lane * 8];
      bf16x8 al = *(const bf16x8*)&AlL[rt * 512 + lane * 8];
#pragma unroll
      for (int n = 0; n < 4; ++n) {
        acc[m][n] = __builtin_amdgcn_mfma_f32_16x16x32_bf16(ah, bh[n], acc[m][n], 0, 0, 0);
        acc[m][n] = __builtin_amdgcn_mfma_f32_16x16x32_bf16(ah, bl[n], acc[m][n], 0, 0, 0);
        acc[m][n] = __builtin_amdgcn_mfma_f32_16x16x32_bf16(al, bh[n], acc[m][n], 0, 0, 0);
      }
    }
  }

  // fused A-norms: each thread staged 4 fixed rows across all K
#pragma unroll
  for (int p = 0; p < 4; ++p) {
    int f = p * 512 + t;
    int row = (f >> 7) * 16 + ((f >> 1) & 15);
    atomicAdd(&ninSq[row], ssA[p]);
  }
  __syncthreads();
  if (t < 256) rnin[t] = 1.0f / fmaxf(sqrtf(ninSq[t]), 1e-12f);
  __syncthreads();

  // normalize + reduce upper diagonals (q = col - row >= 0)
#pragma unroll
  for (int n = 0; n < 4; ++n) {
    int col = wn*64 + n*16 + (lane & 15);
    float rc = rntg_s[col];
#pragma unroll
    for (int m = 0; m < 8; ++m) {
      f32x4 a = acc[m][n];
#pragma unroll
      for (int r = 0; r < 4; ++r) {
        int row = wm*128 + m*16 + (lane >> 4)*4 + r;
        int q = col - row;
        if (q >= 0) atomicAdd(&corrS[q], a[r] * rnin[row] * rc);
      }
    }
  }
  __syncthreads();

  // argmax over p (first max = smallest p wins) -> shift = q_best
  if (t < 256) {
    int q = 255 - t;
    float v = corrS[q] / (float)(256 - q);
    unsigned u = __float_as_uint(v);
    u = (u & 0x80000000u) ? ~u : (u | 0x80000000u);
    unsigned long long key = ((unsigned long long)u << 32) | (unsigned)q;
#pragma unroll
    for (int off = 32; off; off >>= 1) {
      unsigned long long o = __shfl_xor(key, off);
      if (o > key) key = o;
    }
    if ((t & 63) == 0) wkey[t >> 6] = key;
  }
  __syncthreads();
  if (t == 0) {
    unsigned long long k = wkey[0];
#pragma unroll
    for (int i = 1; i < 4; ++i) if (wkey[i] > k) k = wkey[i];
    shift_out[bs] = (int)(k & 0xFFFFFFFFull);
  }
}

// -------- shifted gather --------
__global__ void ct_gather(const float* __restrict__ input,
                          const int* __restrict__ shift,
                          float* __restrict__ out) {
  size_t idx = (size_t)blockIdx.x * blockDim.x + threadIdx.x;  // float4 units
  int w4 = (int)(idx & 63);
  int h  = (int)((idx >> 6) & 255);
  int sc = (int)(idx >> 14);
  int bs = sc / 3;
  int hh = h + shift[bs];
  float4 v = make_float4(0.f, 0.f, 0.f, 0.f);
  if (hh < H_) v = *(const float4*)(input + ((size_t)sc << 16) + (size_t)hh * W_ + w4*4);
  *(float4*)(out + (idx << 2)) = v;
}

extern "C" void kernel_launch(void* const* d_in, const int* in_sizes, int n_in,
                              void* d_out, int out_size, void* d_ws, size_t ws_size,
                              hipStream_t stream) {
  const float* input  = (const float*)d_in[0];
  const float* target = (const float*)d_in[1];
  float* out = (float*)d_out;

  float* rntg  = (float*)d_ws;                      // 2048 f
  int*   shift = (int*)(rntg + 2048);               // 256 i
  ushort* BhG  = (ushort*)(shift + 256);            // 8*24*8192 ushort = 3 MB
  ushort* BlG  = BhG + (size_t)B_ * NT_ * TILE_ELEMS;

  ct_ntg       <<<512, 256, 0, stream>>>(target, rntg);
  ct_bsplit    <<<B_ * NT_, 256, 0, stream>>>(target, BhG, BlG);
  ct_corr_mfma <<<B_ * S_, 512, 0, stream>>>(input, BhG, BlG, rntg, shift);
  ct_gather    <<<(B_*S_*C_*H_*W_/4) / 256, 256, 0, stream>>>(input, shift, out);
}